// Round 6
// baseline (180.735 us; speedup 1.0000x reference)
//
#include <hip/hip_runtime.h>
#include <hip/hip_fp16.h>
#include <cstdint>

typedef int v4i __attribute__((ext_vector_type(4)));

#define AS1C(p) ((const __attribute__((address_space(1))) void*)(p))
#define AS3(p)  ((__attribute__((address_space(3))) void*)(p))

// ---------------------------------------------------------------------------
// Per-row symmetric int8 quantization — single pass, row held in registers.
// ---------------------------------------------------------------------------
__global__ __launch_bounds__(256) void quant_rows(const float* __restrict__ X,
                                                  int8_t* __restrict__ Q,
                                                  float* __restrict__ scales,
                                                  int K) {
    const int row = blockIdx.x;
    const float4* xv = (const float4*)(X + (size_t)row * K);

    float4 v[4];
#pragma unroll
    for (int j = 0; j < 4; ++j) v[j] = xv[threadIdx.x + (j << 8)];

    float m = 0.0f;
#pragma unroll
    for (int j = 0; j < 4; ++j) {
        m = fmaxf(m, fmaxf(fmaxf(fabsf(v[j].x), fabsf(v[j].y)),
                           fmaxf(fabsf(v[j].z), fabsf(v[j].w))));
    }
    for (int off = 32; off > 0; off >>= 1)
        m = fmaxf(m, __shfl_xor(m, off, 64));

    __shared__ float wmax[4];
    __shared__ float s_sc;
    const int lane = threadIdx.x & 63;
    const int wv = threadIdx.x >> 6;
    if (lane == 0) wmax[wv] = m;
    __syncthreads();
    if (threadIdx.x == 0) {
        float mm = fmaxf(fmaxf(wmax[0], wmax[1]), fmaxf(wmax[2], wmax[3]));
        float sc = mm / 127.0f;
        scales[row] = sc;
        s_sc = sc;
    }
    __syncthreads();
    const float sc = s_sc;

    char4* qv = (char4*)(Q + (size_t)row * K);
#pragma unroll
    for (int j = 0; j < 4; ++j) {
        char4 q;
        q.x = (signed char)(int)rintf(v[j].x / sc);
        q.y = (signed char)(int)rintf(v[j].y / sc);
        q.z = (signed char)(int)rintf(v[j].z / sc);
        q.w = (signed char)(int)rintf(v[j].w / sc);
        qv[threadIdx.x + (j << 8)] = q;
    }
}

// ---------------------------------------------------------------------------
// int8 GEMM, 256x256 tile, 512 threads = 8 waves (2M x 4N), per-wave 128x64.
// 4-buffer LDS ring (128 KiB), BK=64 B, register-double-buffered fragments,
// 4 groups/tile of { 3 ds_read (next tile) + 1 global_load_lds + 8 MFMA }.
// T5 scoping: setprio(1) wraps ONLY each 8-MFMA cluster — reads and staging
// run at prio 0. With 2 waves/SIMD in lockstep, this gives the CU scheduler
// the role-split signal: a wave in its MFMA burst out-prioritizes its
// sibling still issuing ds_reads, the two drift into anti-phase, and the
// MFMA-pipe time covers LDS-port time instead of serializing with it.
// (Round-3 had prio(1) spanning the whole tile => no arbitration signal =>
// pipes alternated: measured 2390 cyc/tile = 1306 MFMA + ~1100 LDS serial.)
// vmcnt(4) once per tile retires exactly tile kt+1's staging; one s_barrier
// per tile; sched_barrier(0) fences keep read/MFMA clusters intact.
// ---------------------------------------------------------------------------
__global__ __launch_bounds__(512, 2) void gemm_i8(const int8_t* __restrict__ Aq,
                                                  const int8_t* __restrict__ Bq,
                                                  const float* __restrict__ a_scale,
                                                  const float* __restrict__ w_scale,
                                                  float* __restrict__ out) {
    extern __shared__ __align__(16) int8_t smem[];  // 4 x (A 16K | B 16K)

    const int K = 4096;
    const int bid = blockIdx.x;
    const int wg  = (bid & 7) * 64 + (bid >> 3);  // bijective: 512 = 8 x 64
    const int n0 = (wg & 15) * 256;
    const int m0 = (wg >> 4) * 256;

    const int tid  = threadIdx.x;
    const int lane = tid & 63;
    const int wid  = tid >> 6;
    const int wm   = wid >> 2;
    const int wn   = wid & 3;

    // fragment read offsets (64-B rows, 16-B-chunk XOR swizzle)
    const int rsel  = lane & 15;
    const int kswz  = ((lane >> 4) << 4) ^ (((rsel >> 1) & 3) << 4);
    const int abase = (wm * 128 + rsel) * 64 + kswz;
    const int bbase = 16384 + (wn * 64 + rsel) * 64 + kswz;

    // staging: 512 thr x 16 B = 128 rows/issue; pre-swizzled global source
    const int strow = tid >> 2;
    const int stswz = ((strow >> 1) & 3) << 4;
    const int stcol = ((tid & 3) << 4) ^ stswz;
    const int8_t* gA = Aq + (size_t)(m0 + strow) * K + stcol;
    const int8_t* gB = Bq + (size_t)(n0 + strow) * K + stcol;
    const size_t rstep = (size_t)128 * K;
    const int ldsst = wid * 1024;  // + lane*16 by HW

    v4i acc[8][4] = {};
    v4i aFa[8], aFb[8], bFa[4], bFb[4];

#define STAGE(buf, kt) do {                                                          \
    int8_t* _d = smem + (buf) * 32768;                                               \
    const int8_t* _a = gA + (size_t)(kt) * 64;                                       \
    const int8_t* _b = gB + (size_t)(kt) * 64;                                       \
    __builtin_amdgcn_global_load_lds(AS1C(_a),         AS3(_d + ldsst),         16, 0, 0); \
    __builtin_amdgcn_global_load_lds(AS1C(_a + rstep), AS3(_d + 8192  + ldsst), 16, 0, 0); \
    __builtin_amdgcn_global_load_lds(AS1C(_b),         AS3(_d + 16384 + ldsst), 16, 0, 0); \
    __builtin_amdgcn_global_load_lds(AS1C(_b + rstep), AS3(_d + 24576 + ldsst), 16, 0, 0); \
  } while (0)

    // One mt-major group: {reads + stage issue}@prio0, then 8 MFMAs @prio1.
#define GROUP(g, CA, CB, NA, NB, gsrc, goff)  do {                                   \
    NA[2*(g)]     = *(const v4i*)(bufN + abase + (2*(g))     * 1024);                \
    NA[2*(g) + 1] = *(const v4i*)(bufN + abase + (2*(g) + 1) * 1024);                \
    NB[(g)]       = *(const v4i*)(bufN + bbase + (g) * 1024);                        \
    __builtin_amdgcn_global_load_lds(AS1C(gsrc), AS3(pD + (goff) + ldsst), 16, 0, 0);\
    __builtin_amdgcn_sched_barrier(0);                                               \
    __builtin_amdgcn_s_setprio(1);                                                   \
    _Pragma("unroll")                                                                \
    for (int nt = 0; nt < 4; ++nt) {                                                 \
        acc[2*(g)][nt] = __builtin_amdgcn_mfma_i32_16x16x64_i8(                      \
            CA[2*(g)], CB[nt], acc[2*(g)][nt], 0, 0, 0);                             \
        acc[2*(g)+1][nt] = __builtin_amdgcn_mfma_i32_16x16x64_i8(                    \
            CA[2*(g)+1], CB[nt], acc[2*(g)+1][nt], 0, 0, 0);                         \
    }                                                                                \
    __builtin_amdgcn_s_setprio(0);                                                   \
    __builtin_amdgcn_sched_barrier(0);                                               \
  } while (0)

#define KSTEP(u, CA, CB, NA, NB, kt4) do {                                           \
    const int kt  = (kt4) + (u);                                                     \
    const int8_t* bufN = smem + (((u) + 1) & 3) * 32768;                             \
    int8_t* pD = smem + (((u) + 3) & 3) * 32768;                                     \
    const int ktp = (kt + 3 < 64) ? (kt + 3) : 63;                                   \
    const int8_t* _a = gA + (size_t)ktp * 64;                                        \
    const int8_t* _b = gB + (size_t)ktp * 64;                                        \
    asm volatile("s_waitcnt vmcnt(4)" ::: "memory");                                 \
    __builtin_amdgcn_s_barrier();                                                    \
    GROUP(0, CA, CB, NA, NB, _a,         0);                                         \
    GROUP(1, CA, CB, NA, NB, _a + rstep, 8192);                                      \
    GROUP(2, CA, CB, NA, NB, _b,         16384);                                     \
    GROUP(3, CA, CB, NA, NB, _b + rstep, 24576);                                     \
  } while (0)

    // ---- prologue: stage tiles 0..2; retire tile 0; load its fragments
    STAGE(0, 0); STAGE(1, 1); STAGE(2, 2);
    asm volatile("s_waitcnt vmcnt(8)" ::: "memory");
    __builtin_amdgcn_s_barrier();
#pragma unroll
    for (int mt = 0; mt < 8; ++mt) aFa[mt] = *(const v4i*)(smem + abase + mt * 1024);
#pragma unroll
    for (int nt = 0; nt < 4; ++nt) bFa[nt] = *(const v4i*)(smem + bbase + nt * 1024);

    for (int kt4 = 0; kt4 < 64; kt4 += 4) {
        KSTEP(0, aFa, bFa, aFb, bFb, kt4);
        KSTEP(1, aFb, bFb, aFa, bFa, kt4);
        KSTEP(2, aFa, bFa, aFb, bFb, kt4);
        KSTEP(3, aFb, bFb, aFa, bFa, kt4);
    }

    // epilogue: C/D layout col = lane&15 (N), row = (lane>>4)*4 + reg (M)
    const int r0  = (lane >> 4) << 2;
    const int col = lane & 15;
#pragma unroll
    for (int mt = 0; mt < 8; ++mt) {
        const int tbase = m0 + wm * 128 + mt * 16 + r0;
        float as[4];
#pragma unroll
        for (int r = 0; r < 4; ++r) as[r] = a_scale[tbase + r];
#pragma unroll
        for (int nt = 0; nt < 4; ++nt) {
            const int o = n0 + wn * 64 + nt * 16 + col;
            const float wsc = w_scale[o];
#pragma unroll
            for (int r = 0; r < 4; ++r) {
                float v = (float)acc[mt][nt][r] * as[r] * wsc;
                out[(size_t)(tbase + r) * 4096 + o] = __half2float(__float2half_rn(v));
            }
        }
    }
#undef KSTEP
#undef GROUP
#undef STAGE
}

extern "C" void kernel_launch(void* const* d_in, const int* in_sizes, int n_in,
                              void* d_out, int out_size, void* d_ws, size_t ws_size,
                              hipStream_t stream) {
    const float* input_act = (const float*)d_in[0];  // [4,2048,4096] = [8192,4096]
    const float* weight    = (const float*)d_in[1];  // [4096,4096]
    float* out = (float*)d_out;

    const int K = 4096, O = 4096, T = 8192;

    int8_t* x_q = (int8_t*)d_ws;
    int8_t* w_q = x_q + (size_t)T * K;
    float* a_scale = (float*)(w_q + (size_t)O * K);
    float* w_scale = a_scale + T;

    static bool attr_done = false;
    if (!attr_done) {
        hipFuncSetAttribute(reinterpret_cast<const void*>(gemm_i8),
                            hipFuncAttributeMaxDynamicSharedMemorySize, 131072);
        attr_done = true;
    }

    quant_rows<<<T, 256, 0, stream>>>(input_act, x_q, a_scale, K);
    quant_rows<<<O, 256, 0, stream>>>(weight, w_q, w_scale, K);

    dim3 grid(512);  // (8192/256) x (4096/256), XCD-swizzled in-kernel
    gemm_i8<<<grid, 512, 131072, stream>>>(x_q, w_q, a_scale, w_scale, out);
}

// Round 7
// 177.071 us; speedup vs baseline: 1.0207x; 1.0207x over previous
//
#include <hip/hip_runtime.h>
#include <hip/hip_fp16.h>
#include <cstdint>

typedef int v4i __attribute__((ext_vector_type(4)));

#define AS1C(p) ((const __attribute__((address_space(1))) void*)(p))
#define AS3(p)  ((__attribute__((address_space(3))) void*)(p))

// ---------------------------------------------------------------------------
// Fused per-row symmetric int8 quantization for BOTH activations and weights:
// one launch, 12288 blocks (rows 0..8191 = activations, 8192..12287 = weight).
// Single pass — the 16 KB row lives in 16 VGPRs between absmax and quantize.
// ---------------------------------------------------------------------------
__global__ __launch_bounds__(256) void quant_fused(const float* __restrict__ X,
                                                   const float* __restrict__ W,
                                                   int8_t* __restrict__ Xq,
                                                   int8_t* __restrict__ Wq,
                                                   float* __restrict__ a_scale,
                                                   float* __restrict__ w_scale) {
    const int row = blockIdx.x;
    const float* src;
    int8_t* dst;
    float* scp;
    if (row < 8192) {
        src = X + (size_t)row * 4096;  dst = Xq + (size_t)row * 4096;  scp = a_scale + row;
    } else {
        const int r = row - 8192;
        src = W + (size_t)r * 4096;    dst = Wq + (size_t)r * 4096;    scp = w_scale + r;
    }
    const float4* xv = (const float4*)src;

    float4 v[4];
#pragma unroll
    for (int j = 0; j < 4; ++j) v[j] = xv[threadIdx.x + (j << 8)];

    float m = 0.0f;
#pragma unroll
    for (int j = 0; j < 4; ++j) {
        m = fmaxf(m, fmaxf(fmaxf(fabsf(v[j].x), fabsf(v[j].y)),
                           fmaxf(fabsf(v[j].z), fabsf(v[j].w))));
    }
    for (int off = 32; off > 0; off >>= 1)
        m = fmaxf(m, __shfl_xor(m, off, 64));

    __shared__ float wmax[4];
    __shared__ float s_sc;
    const int lane = threadIdx.x & 63;
    const int wv = threadIdx.x >> 6;
    if (lane == 0) wmax[wv] = m;
    __syncthreads();
    if (threadIdx.x == 0) {
        float mm = fmaxf(fmaxf(wmax[0], wmax[1]), fmaxf(wmax[2], wmax[3]));
        float sc = mm / 127.0f;
        *scp = sc;
        s_sc = sc;
    }
    __syncthreads();
    const float sc = s_sc;

    char4* qv = (char4*)dst;
#pragma unroll
    for (int j = 0; j < 4; ++j) {
        char4 q;
        q.x = (signed char)(int)rintf(v[j].x / sc);
        q.y = (signed char)(int)rintf(v[j].y / sc);
        q.z = (signed char)(int)rintf(v[j].z / sc);
        q.w = (signed char)(int)rintf(v[j].w / sc);
        qv[threadIdx.x + (j << 8)] = q;
    }
}

// ---------------------------------------------------------------------------
// int8 GEMM, 256x256 tile, 512 threads = 8 waves (2M x 4N), per-wave 128x64.
// 4-buffer LDS ring (128 KiB), BK=64 B, register-double-buffered fragments,
// 4 groups/tile of { 3 ds_read (next tile) + 1 global_load_lds + 8 MFMA }.
// NEW — static ROLE SPLIT by SIMD sibling: waves 0-3 (SIMD 0-3) run
// {reads -> MFMA} per group; waves 4-7 (the SAME SIMDs, wid%4) run
// {MFMA -> reads}. Every SIMD then has one wave feeding the MFMA pipe while
// its sibling occupies the LDS port, BY CONSTRUCTION — fixing the lockstep
// that the tile-head vmcnt (a common release event) re-imposes each tile
// and that setprio alone could not break (r6: +2%). Legal only because of
// the cross-tile register double-buffer: lag waves' MFMAs consume last-tile
// registers, so they can fire before this tile's reads. Barrier and vmcnt
// counts are identical in both role branches (branch hoisted outside the
// K-loop; one s_barrier + one vmcnt(4) per tile for every wave).
// ---------------------------------------------------------------------------
__global__ __launch_bounds__(512, 2) void gemm_i8(const int8_t* __restrict__ Aq,
                                                  const int8_t* __restrict__ Bq,
                                                  const float* __restrict__ a_scale,
                                                  const float* __restrict__ w_scale,
                                                  float* __restrict__ out) {
    extern __shared__ __align__(16) int8_t smem[];  // 4 x (A 16K | B 16K)

    const int K = 4096;
    const int bid = blockIdx.x;
    const int wg  = (bid & 7) * 64 + (bid >> 3);  // bijective: 512 = 8 x 64
    const int n0 = (wg & 15) * 256;
    const int m0 = (wg >> 4) * 256;

    const int tid  = threadIdx.x;
    const int lane = tid & 63;
    const int wid  = tid >> 6;
    const int wm   = wid >> 2;
    const int wn   = wid & 3;

    // fragment read offsets (64-B rows, 16-B-chunk XOR swizzle)
    const int rsel  = lane & 15;
    const int kswz  = ((lane >> 4) << 4) ^ (((rsel >> 1) & 3) << 4);
    const int abase = (wm * 128 + rsel) * 64 + kswz;
    const int bbase = 16384 + (wn * 64 + rsel) * 64 + kswz;

    // staging: 512 thr x 16 B = 128 rows/issue; pre-swizzled global source
    const int strow = tid >> 2;
    const int stswz = ((strow >> 1) & 3) << 4;
    const int stcol = ((tid & 3) << 4) ^ stswz;
    const int8_t* gA = Aq + (size_t)(m0 + strow) * K + stcol;
    const int8_t* gB = Bq + (size_t)(n0 + strow) * K + stcol;
    const size_t rstep = (size_t)128 * K;
    const int ldsst = wid * 1024;  // + lane*16 by HW

    v4i acc[8][4] = {};
    v4i aFa[8], aFb[8], bFa[4], bFb[4];

#define STAGE(buf, kt) do {                                                          \
    int8_t* _d = smem + (buf) * 32768;                                               \
    const int8_t* _a = gA + (size_t)(kt) * 64;                                       \
    const int8_t* _b = gB + (size_t)(kt) * 64;                                       \
    __builtin_amdgcn_global_load_lds(AS1C(_a),         AS3(_d + ldsst),         16, 0, 0); \
    __builtin_amdgcn_global_load_lds(AS1C(_a + rstep), AS3(_d + 8192  + ldsst), 16, 0, 0); \
    __builtin_amdgcn_global_load_lds(AS1C(_b),         AS3(_d + 16384 + ldsst), 16, 0, 0); \
    __builtin_amdgcn_global_load_lds(AS1C(_b + rstep), AS3(_d + 24576 + ldsst), 16, 0, 0); \
  } while (0)

#define READS(g, NA, NB, gsrc, goff) do {                                            \
    NA[2*(g)]     = *(const v4i*)(bufN + abase + (2*(g))     * 1024);                \
    NA[2*(g) + 1] = *(const v4i*)(bufN + abase + (2*(g) + 1) * 1024);                \
    NB[(g)]       = *(const v4i*)(bufN + bbase + (g) * 1024);                        \
    __builtin_amdgcn_global_load_lds(AS1C(gsrc), AS3(pD + (goff) + ldsst), 16, 0, 0);\
  } while (0)

#define MFMAS(g, CA, CB) do {                                                        \
    __builtin_amdgcn_s_setprio(1);                                                   \
    _Pragma("unroll")                                                                \
    for (int nt = 0; nt < 4; ++nt) {                                                 \
        acc[2*(g)][nt] = __builtin_amdgcn_mfma_i32_16x16x64_i8(                      \
            CA[2*(g)], CB[nt], acc[2*(g)][nt], 0, 0, 0);                             \
        acc[2*(g)+1][nt] = __builtin_amdgcn_mfma_i32_16x16x64_i8(                    \
            CA[2*(g)+1], CB[nt], acc[2*(g)+1][nt], 0, 0, 0);                         \
    }                                                                                \
    __builtin_amdgcn_s_setprio(0);                                                   \
  } while (0)

    // lead role: reads feed the LDS port while the sibling's MFMAs run
#define GROUP_RW(g, CA, CB, NA, NB, gsrc, goff)  do {                                \
    READS(g, NA, NB, gsrc, goff);                                                    \
    __builtin_amdgcn_sched_barrier(0);                                               \
    MFMAS(g, CA, CB);                                                                \
    __builtin_amdgcn_sched_barrier(0);                                               \
  } while (0)

    // lag role: MFMA first (consumes last-tile registers), reads after
#define GROUP_WR(g, CA, CB, NA, NB, gsrc, goff)  do {                                \
    MFMAS(g, CA, CB);                                                                \
    __builtin_amdgcn_sched_barrier(0);                                               \
    READS(g, NA, NB, gsrc, goff);                                                    \
    __builtin_amdgcn_sched_barrier(0);                                               \
  } while (0)

#define KSTEP(G, u, CA, CB, NA, NB, kt4) do {                                        \
    const int kt  = (kt4) + (u);                                                     \
    const int8_t* bufN = smem + (((u) + 1) & 3) * 32768;                             \
    int8_t* pD = smem + (((u) + 3) & 3) * 32768;                                     \
    const int ktp = (kt + 3 < 64) ? (kt + 3) : 63;                                   \
    const int8_t* _a = gA + (size_t)ktp * 64;                                        \
    const int8_t* _b = gB + (size_t)ktp * 64;                                        \
    asm volatile("s_waitcnt vmcnt(4)" ::: "memory");                                 \
    __builtin_amdgcn_s_barrier();                                                    \
    __builtin_amdgcn_sched_barrier(0);                                               \
    G(0, CA, CB, NA, NB, _a,         0);                                             \
    G(1, CA, CB, NA, NB, _a + rstep, 8192);                                          \
    G(2, CA, CB, NA, NB, _b,         16384);                                         \
    G(3, CA, CB, NA, NB, _b + rstep, 24576);                                         \
  } while (0)

    // ---- prologue: stage tiles 0..2; retire tile 0; load its fragments
    STAGE(0, 0); STAGE(1, 1); STAGE(2, 2);
    asm volatile("s_waitcnt vmcnt(8)" ::: "memory");
    __builtin_amdgcn_s_barrier();
#pragma unroll
    for (int mt = 0; mt < 8; ++mt) aFa[mt] = *(const v4i*)(smem + abase + mt * 1024);
#pragma unroll
    for (int nt = 0; nt < 4; ++nt) bFa[nt] = *(const v4i*)(smem + bbase + nt * 1024);

    if (wid < 4) {  // lead waves: one per SIMD (wid%4 = SIMD id)
        for (int kt4 = 0; kt4 < 64; kt4 += 4) {
            KSTEP(GROUP_RW, 0, aFa, bFa, aFb, bFb, kt4);
            KSTEP(GROUP_RW, 1, aFb, bFb, aFa, bFa, kt4);
            KSTEP(GROUP_RW, 2, aFa, bFa, aFb, bFb, kt4);
            KSTEP(GROUP_RW, 3, aFb, bFb, aFa, bFa, kt4);
        }
    } else {        // lag waves: the SIMD siblings, anti-phased by construction
        for (int kt4 = 0; kt4 < 64; kt4 += 4) {
            KSTEP(GROUP_WR, 0, aFa, bFa, aFb, bFb, kt4);
            KSTEP(GROUP_WR, 1, aFb, bFb, aFa, bFa, kt4);
            KSTEP(GROUP_WR, 2, aFa, bFa, aFb, bFb, kt4);
            KSTEP(GROUP_WR, 3, aFb, bFb, aFa, bFa, kt4);
        }
    }

    // epilogue: C/D layout col = lane&15 (N), row = (lane>>4)*4 + reg (M)
    const int r0  = (lane >> 4) << 2;
    const int col = lane & 15;
#pragma unroll
    for (int mt = 0; mt < 8; ++mt) {
        const int tbase = m0 + wm * 128 + mt * 16 + r0;
        float as[4];
#pragma unroll
        for (int r = 0; r < 4; ++r) as[r] = a_scale[tbase + r];
#pragma unroll
        for (int nt = 0; nt < 4; ++nt) {
            const int o = n0 + wn * 64 + nt * 16 + col;
            const float wsc = w_scale[o];
#pragma unroll
            for (int r = 0; r < 4; ++r) {
                float v = (float)acc[mt][nt][r] * as[r] * wsc;
                out[(size_t)(tbase + r) * 4096 + o] = __half2float(__float2half_rn(v));
            }
        }
    }
#undef KSTEP
#undef GROUP_RW
#undef GROUP_WR
#undef MFMAS
#undef READS
#undef STAGE
}

extern "C" void kernel_launch(void* const* d_in, const int* in_sizes, int n_in,
                              void* d_out, int out_size, void* d_ws, size_t ws_size,
                              hipStream_t stream) {
    const float* input_act = (const float*)d_in[0];  // [4,2048,4096] = [8192,4096]
    const float* weight    = (const float*)d_in[1];  // [4096,4096]
    float* out = (float*)d_out;

    const int K = 4096, O = 4096, T = 8192;

    int8_t* x_q = (int8_t*)d_ws;
    int8_t* w_q = x_q + (size_t)T * K;
    float* a_scale = (float*)(w_q + (size_t)O * K);
    float* w_scale = a_scale + T;

    static bool attr_done = false;
    if (!attr_done) {
        hipFuncSetAttribute(reinterpret_cast<const void*>(gemm_i8),
                            hipFuncAttributeMaxDynamicSharedMemorySize, 131072);
        attr_done = true;
    }

    quant_fused<<<T + O, 256, 0, stream>>>(input_act, weight, x_q, w_q,
                                           a_scale, w_scale);

    dim3 grid(512);  // (8192/256) x (4096/256), XCD-swizzled in-kernel
    gemm_i8<<<grid, 512, 131072, stream>>>(x_q, w_q, a_scale, w_scale, out);
}